// Round 1
// baseline (162.837 us; speedup 1.0000x reference)
//
#include <hip/hip_runtime.h>

#define NV 64
#define NP 2016   // 64*63/2
#define ALPHA_T (20.0f / 90.0f)

__global__ __launch_bounds__(256) void score_kernel(
    const float* __restrict__ views,   // (B, 64, 7)
    const float* __restrict__ pairs,   // (B, 2016, 3)
    const float* __restrict__ s_a1,
    const float* __restrict__ s_a2,
    const float* __restrict__ s_gsd,
    const float* __restrict__ s_scale,
    const float* __restrict__ s_nrm,
    const float* __restrict__ s_dist,
    float* __restrict__ out)
{
    const int b = blockIdx.x;
    const int t = threadIdx.x;

    __shared__ float gv[NV];
    __shared__ float wsum[4];

    // scalars (L2-resident after first block)
    const float a1 = s_a1[0];
    const float a2 = s_a2[0];
    const float gsd_s   = s_gsd[0];
    const float scale_s = s_scale[0];
    const float nrm_s   = s_nrm[0];
    const float dist_s  = s_dist[0];

    const float ia1     = 0.5f / (a1 * a1);
    const float ia2     = 0.5f / (a2 * a2);
    const float c_gsd   = 0.5f / (gsd_s * gsd_s);
    const float c_scale = 0.5f / (scale_s * scale_s);
    const float c_nrm   = 0.5f / (nrm_s * nrm_s);
    const float c_dist  = 0.5f / (dist_s * dist_s);

    // per-view combined factor: mask * gsd * nrm * dist (single exp)
    if (t < NV) {
        const float* vb = views + ((long)b * NV + t) * 7;
        float m  = (vb[0] == 1.0f) ? 1.0f : 0.0f;
        float x4 = vb[4], x5 = vb[5], x6 = vb[6];
        float x4sq = x4 * x4;
        float e = x4sq * x4sq * c_gsd + x5 * x5 * c_nrm + x6 * x6 * c_dist;
        gv[t] = m * __expf(-e);
    }
    __syncthreads();

    const float* pb = pairs + (long)b * NP * 3;
    float acc = 0.0f;

    for (int p = t; p < NP; p += 256) {
        float pm_raw = pb[3 * p + 0];
        float a      = pb[3 * p + 1];
        float s      = pb[3 * p + 2];

        // decode triu indices: i = floor((127 - sqrt(16129 - 8p)) / 2), exact at
        // row boundaries (disc is a perfect square there); fix-up for safety.
        int i = (int)((127.0f - sqrtf((float)(16129 - 8 * p))) * 0.5f);
        int Si = (i * (127 - i)) >> 1;
        if (Si > p) { --i; Si = (i * (127 - i)) >> 1; }
        else {
            int Si1 = ((i + 1) * (126 - i)) >> 1;
            if (Si1 <= p) { i = i + 1; Si = Si1; }
        }
        int j = i + 1 + (p - Si);

        float coef = (a < ALPHA_T) ? ia1 : ia2;
        float base = __expf(-(a * a * coef + s * s * c_scale));
        if (a == ALPHA_T) base = 0.0f;   // sig=0, expo=0 -> exp(-1/0) = 0

        float v = base * gv[i] * gv[j];
        acc += (pm_raw != 0.0f) ? v : 0.0f;
    }

    // wave-64 reduce
    #pragma unroll
    for (int off = 32; off > 0; off >>= 1)
        acc += __shfl_down(acc, off, 64);

    const int wid  = t >> 6;
    const int lane = t & 63;
    if (lane == 0) wsum[wid] = acc;
    __syncthreads();
    if (t == 0) out[b] = wsum[0] + wsum[1] + wsum[2] + wsum[3];
}

extern "C" void kernel_launch(void* const* d_in, const int* in_sizes, int n_in,
                              void* d_out, int out_size, void* d_ws, size_t ws_size,
                              hipStream_t stream) {
    const float* views = (const float*)d_in[0];
    const float* pairs = (const float*)d_in[1];
    // d_in[2] = point_attribute (unused by the reference computation)
    const float* a1    = (const float*)d_in[3];
    const float* a2    = (const float*)d_in[4];
    const float* gsd   = (const float*)d_in[5];
    const float* scale = (const float*)d_in[6];
    const float* nrm   = (const float*)d_in[7];
    const float* dist  = (const float*)d_in[8];
    float* out = (float*)d_out;

    const int B = in_sizes[0] / (NV * 7);

    score_kernel<<<B, 256, 0, stream>>>(views, pairs, a1, a2, gsd, scale, nrm, dist, out);
}

// Round 2
// 161.693 us; speedup vs baseline: 1.0071x; 1.0071x over previous
//
#include <hip/hip_runtime.h>

#define NV 64
#define NP 2016            // 64*63/2
#define NT 504             // NP/4 pair-groups per batch element
#define ALPHA_T (20.0f / 90.0f)

__global__ __launch_bounds__(256) void score_kernel(
    const float* __restrict__ views,   // (B, 64, 7)
    const float* __restrict__ pairs,   // (B, 2016, 3)
    const float* __restrict__ s_a1,
    const float* __restrict__ s_a2,
    const float* __restrict__ s_gsd,
    const float* __restrict__ s_scale,
    const float* __restrict__ s_nrm,
    const float* __restrict__ s_dist,
    float* __restrict__ out)
{
    const int b = blockIdx.x;
    const int t = threadIdx.x;

    __shared__ float gv[NV];
    __shared__ float wsum[4];

    const float a1 = s_a1[0];
    const float a2 = s_a2[0];
    const float gsd_s   = s_gsd[0];
    const float scale_s = s_scale[0];
    const float nrm_s   = s_nrm[0];
    const float dist_s  = s_dist[0];

    const float ia1     = 0.5f / (a1 * a1);
    const float ia2     = 0.5f / (a2 * a2);
    const float c_gsd   = 0.5f / (gsd_s * gsd_s);
    const float c_scale = 0.5f / (scale_s * scale_s);
    const float c_nrm   = 0.5f / (nrm_s * nrm_s);
    const float c_dist  = 0.5f / (dist_s * dist_s);

    // per-view combined factor: mask * gsd * nrm * dist in ONE exp
    if (t < NV) {
        const float* vb = views + ((size_t)b * NV + t) * 7;
        float m  = (vb[0] == 1.0f) ? 1.0f : 0.0f;
        float x4 = vb[4], x5 = vb[5], x6 = vb[6];
        float x4sq = x4 * x4;
        float e = x4sq * x4sq * c_gsd + x5 * x5 * c_nrm + x6 * x6 * c_dist;
        gv[t] = m * __expf(-e);
    }
    __syncthreads();

    // 4 pairs per task: 48 B = 3 x float4, exactly aligned (b*NP*3*4 % 16 == 0)
    const float4* pb4 = (const float4*)(pairs + (size_t)b * NP * 3);
    float acc = 0.0f;

    for (int task = t; task < NT; task += 256) {
        float4 q0 = pb4[3 * task + 0];
        float4 q1 = pb4[3 * task + 1];
        float4 q2 = pb4[3 * task + 2];

        // decode (i,j) for first pair of the group; sqrt amortized over 4 pairs
        int p = 4 * task;
        int i = (int)((127.0f - sqrtf((float)(16129 - 8 * p))) * 0.5f);
        int Si = (i * (127 - i)) >> 1;
        if (Si > p) { --i; Si = (i * (127 - i)) >> 1; }
        else {
            int Si1 = ((i + 1) * (126 - i)) >> 1;
            if (Si1 <= p) { i = i + 1; Si = Si1; }
        }
        int j = i + 1 + (p - Si);

        const float pm[4] = {q0.x, q0.w, q1.z, q2.y};
        const float av[4] = {q0.y, q1.x, q1.w, q2.z};
        const float sv[4] = {q0.z, q1.y, q2.x, q2.w};

        #pragma unroll
        for (int u = 0; u < 4; ++u) {
            float a = av[u], s = sv[u];
            float coef = (a < ALPHA_T) ? ia1 : ia2;
            float base = __expf(-(a * a * coef + s * s * c_scale));
            if (a == ALPHA_T) base = 0.0f;   // sigma=0, expo=0 -> exp(-1/0)=0
            float v = base * gv[i] * gv[j];
            acc += (pm[u] != 0.0f) ? v : 0.0f;
            // advance to next pair; each row has >=1 pair so one wrap check suffices
            ++j;
            if (j >= NV) { ++i; j = i + 1; }
        }
    }

    // wave-64 butterfly reduce
    #pragma unroll
    for (int off = 32; off > 0; off >>= 1)
        acc += __shfl_down(acc, off, 64);

    const int wid  = t >> 6;
    const int lane = t & 63;
    if (lane == 0) wsum[wid] = acc;
    __syncthreads();
    if (t == 0) out[b] = wsum[0] + wsum[1] + wsum[2] + wsum[3];
}

extern "C" void kernel_launch(void* const* d_in, const int* in_sizes, int n_in,
                              void* d_out, int out_size, void* d_ws, size_t ws_size,
                              hipStream_t stream) {
    const float* views = (const float*)d_in[0];
    const float* pairs = (const float*)d_in[1];
    // d_in[2] = point_attribute (unused by the reference computation)
    const float* a1    = (const float*)d_in[3];
    const float* a2    = (const float*)d_in[4];
    const float* gsd   = (const float*)d_in[5];
    const float* scale = (const float*)d_in[6];
    const float* nrm   = (const float*)d_in[7];
    const float* dist  = (const float*)d_in[8];
    float* out = (float*)d_out;

    const int B = in_sizes[0] / (NV * 7);

    score_kernel<<<B, 256, 0, stream>>>(views, pairs, a1, a2, gsd, scale, nrm, dist, out);
}